// Round 10
// baseline (159.574 us; speedup 1.0000x reference)
//
#include <hip/hip_runtime.h>
#include <hip/hip_bf16.h>
#include <stdint.h>

// pooled[b,i,:] = bias + sum_{j!=i} W_cell(b,i,j) . hid[b,j,:]
// R10 = R9 + 2x waves, 2x shorter chains. gp_main: 1024 blocks x 4 independent
// waves (no intra-loop barriers). Wave = (b, hoq 16-ho slice, cq of 8 cells):
//   stage-1: z(64 j x 16 ho) = hid @ W_c^T   (16 MFMA; A hoisted, B from
//            XCD-local L2-resident Wb)
//   z -> wave-private 2KB LDS (2-way-max swizzle), transpose read
//   stage-2: acc(64 i x 16 ho) += mask @ z   (8 MFMA; mask from hoisted cellt)
// XCD swizzle: bid&7 = XCD owns b in [xcd*8, xcd*8+8) -> per-XCD L2 set =
// Wb 2MB + Hb slice 128KB + cellt slice 32KB (resident; R9-verified FETCH 17MB).

typedef __attribute__((ext_vector_type(8))) short bf16x8;
typedef __attribute__((ext_vector_type(4))) float f32x4;
typedef unsigned int u32;

#define NCHUNK 8   // partial slices (cq)

__device__ inline unsigned short bf16bits(float x) {
    __hip_bfloat16 h = __float2bfloat16(x);
    return *reinterpret_cast<unsigned short*>(&h);
}

// zscr swizzle: bijective, 2-way-max banks on write AND read (derived R10)
__device__ inline int zswz(int jp, int l15) {
    int X = ((((jp >> 1) ^ (jp >> 2)) & 1) << 4)
          | (((jp >> 2) & 1) << 3)
          | (((jp >> 3) & 1) << 2);
    return (jp * 16 + l15) ^ X;
}

// ---- prep: 384 blocks x 256 thr ----
//  [0,256):   W -> Wb bf16 [c][hg][ho][e]      (c = bid>>2, ho-quarter = bid&3)
//  [256,320): cell table for b = bid-256
//  [320,384): hid -> Hb bf16 [b][hg][j][e]     (frag-linear)
__global__ __launch_bounds__(256)
void gp_prep(const float* __restrict__ W, const float* __restrict__ pos,
             const float* __restrict__ hid,
             __hip_bfloat16* __restrict__ Wb,      // [64][16][128][8]
             unsigned char* __restrict__ cellt_g,  // [64][64][64]
             __hip_bfloat16* __restrict__ Hb)      // [64][16][64][8]
{
    const int bid = blockIdx.x, t = threadIdx.x;
    if (bid < 256) {
        __shared__ __attribute__((aligned(16))) __hip_bfloat16 Wl[32][136];
        const int c = bid >> 2, q = bid & 3;
        #pragma unroll
        for (int it = 0; it < 4; ++it) {
            int idx = it * 256 + t;           // 1024 float4s
            int r = idx >> 5, k4 = idx & 31;
            float4 v = *(const float4*)(W + (size_t)(q * 32 + r) * 8192 + c * 128 + k4 * 4);
            __hip_bfloat16* d = &Wl[r][k4 * 4];
            d[0] = __float2bfloat16(v.x); d[1] = __float2bfloat16(v.y);
            d[2] = __float2bfloat16(v.z); d[3] = __float2bfloat16(v.w);
        }
        __syncthreads();
        #pragma unroll
        for (int it = 0; it < 2; ++it) {
            int idx = it * 256 + t;           // 512: hg(16) x hol(32)
            int hg = idx >> 5, hol = idx & 31;
            bf16x8 v = *(const bf16x8*)&Wl[hol][hg * 8];
            *(bf16x8*)(Wb + (size_t)c * 16384 + hg * 1024 + (q * 32 + hol) * 8) = v;
        }
    } else if (bid < 320) {
        __shared__ float ps[128];
        const int b = bid - 256;
        if (t < 128) ps[t] = pos[(size_t)b * 128 + t];
        __syncthreads();
        #pragma unroll
        for (int qq = 0; qq < 16; ++qq) {
            int idx = qq * 256 + t;           // 4096: i x j
            int i = idx >> 6, j = idx & 63;
            float rx = ps[j * 2 + 0] - ps[i * 2 + 0];
            float ry = ps[j * 2 + 1] - ps[i * 2 + 1];
            int gx = (int)((rx + 2.0f) * 2.0f);
            int gy = (int)((ry + 2.0f) * 2.0f);
            gx = gx < 0 ? 0 : (gx > 7 ? 7 : gx);
            gy = gy < 0 ? 0 : (gy > 7 ? 7 : gy);
            cellt_g[(size_t)b * 4096 + idx] =
                (i == j) ? 255 : (unsigned char)(gx * 8 + gy);
        }
    } else {
        const int b = bid - 320;
        #pragma unroll
        for (int q = 0; q < 4; ++q) {
            int idx = q * 256 + t;            // 1024: hg(16) x j(64)
            int hg = idx >> 6, j = idx & 63;
            const float* src = hid + ((size_t)b * 64 + j) * 128 + hg * 8;
            float4 v0 = *(const float4*)src;
            float4 v1 = *(const float4*)(src + 4);
            union { unsigned short us[8]; bf16x8 v; } pk;
            pk.us[0] = bf16bits(v0.x); pk.us[1] = bf16bits(v0.y);
            pk.us[2] = bf16bits(v0.z); pk.us[3] = bf16bits(v0.w);
            pk.us[4] = bf16bits(v1.x); pk.us[5] = bf16bits(v1.y);
            pk.us[6] = bf16bits(v1.z); pk.us[7] = bf16bits(v1.w);
            *(bf16x8*)(Hb + (size_t)b * 8192 + (size_t)idx * 8) = pk.v;
        }
    }
}

// ---- main: 1024 blocks x 256 thr (4 independent waves) ----
__global__ __launch_bounds__(256, 4)
void gp_main(const __hip_bfloat16* __restrict__ Hb,
             const unsigned char* __restrict__ cellt_g,
             const __hip_bfloat16* __restrict__ Wb,
             float* __restrict__ partial)
{
    __shared__ __attribute__((aligned(16))) u32 zscr[4][512];  // 2KB per wave

    const int bid = blockIdx.x;
    const int xcd = bid & 7;
    const int r = bid >> 3;              // 0..127: blocal(8) x hoq(8) x cqg(2)
    const int blocal = r >> 4;
    const int hoq = (r >> 1) & 7;        // 16-ho slice
    const int cqg = r & 1;
    const int b = xcd * 8 + blocal;

    const int t = threadIdx.x;
    const int w = t >> 6;
    const int cq = cqg * 4 + w;          // wave's 8-cell chunk
    const int lane = t & 63;
    const int l15 = lane & 15, kg = lane >> 4;
    u32* zw = &zscr[w][0];

    // hoisted cellt bytes (i = mt*16+l15, j = ks2*32+kg*8 .. +8)
    uint2 cs[4][2];
    #pragma unroll
    for (int mt = 0; mt < 4; ++mt)
        #pragma unroll
        for (int ks2 = 0; ks2 < 2; ++ks2)
            cs[mt][ks2] = *(const uint2*)(cellt_g + (size_t)b * 4096 +
                                          (mt * 16 + l15) * 64 + ks2 * 32 + kg * 8);

    // hoisted hid A-frags: a[jt][ks], row j=jt*16+l15, k=(ks*4+kg)*8..
    bf16x8 a[4][4];
    #pragma unroll
    for (int jt = 0; jt < 4; ++jt)
        #pragma unroll
        for (int ks = 0; ks < 4; ++ks)
            a[jt][ks] = *(const bf16x8*)(Hb + (size_t)b * 8192 +
                                         ((ks * 4 + kg) * 64 + jt * 16 + l15) * 8);

    f32x4 acc[4];
    #pragma unroll
    for (int mt = 0; mt < 4; ++mt) acc[mt] = (f32x4){0.f, 0.f, 0.f, 0.f};

    #pragma unroll 2
    for (int cc = 0; cc < 8; ++cc) {
        const int c = cq * 8 + cc;

        // W B-frags (XCD-L2-resident): col ho = hoq*16+l15, k=(ks*4+kg)*8..
        bf16x8 wf[4];
        #pragma unroll
        for (int ks = 0; ks < 4; ++ks)
            wf[ks] = *(const bf16x8*)(Wb + (size_t)c * 16384 +
                ((ks * 4 + kg) * 128 + hoq * 16 + l15) * 8);

        // stage-1: z[jt] = hid(j x h) @ W_c^T(h x ho16), 16 MFMA
        f32x4 z[4];
        #pragma unroll
        for (int jt = 0; jt < 4; ++jt) z[jt] = (f32x4){0.f, 0.f, 0.f, 0.f};
        #pragma unroll
        for (int ks = 0; ks < 4; ++ks)
            #pragma unroll
            for (int jt = 0; jt < 4; ++jt)
                z[jt] = __builtin_amdgcn_mfma_f32_16x16x32_bf16(a[jt][ks], wf[ks], z[jt], 0, 0, 0);

        // pack z -> zw: word jp=j/2 holds (j even lo, j odd hi); D: col=l15=ho,
        // row j = jt*16 + kg*4 + r  ->  jp = jt*8 + kg*2 (+1)
        #pragma unroll
        for (int jt = 0; jt < 4; ++jt) {
            u32 p0 = (u32)bf16bits(z[jt][0]) | ((u32)bf16bits(z[jt][1]) << 16);
            u32 p1 = (u32)bf16bits(z[jt][2]) | ((u32)bf16bits(z[jt][3]) << 16);
            int a0 = zswz(jt * 8 + kg * 2, l15);
            zw[a0] = p0;
            zw[a0 ^ 16] = p1;   // jp+1: same X, bit4 flips
        }

        // transpose read: b2[ks2] word u <- jp = ks2*16 + kg*4 + u
        bf16x8 b2[2];
        #pragma unroll
        for (int ks2 = 0; ks2 < 2; ++ks2) {
            union { u32 wd[4]; bf16x8 v; } rr;
            #pragma unroll
            for (int u = 0; u < 4; ++u)
                rr.wd[u] = zw[zswz(ks2 * 16 + kg * 4 + u, l15)];
            b2[ks2] = rr.v;
        }

        // stage-2: acc(i,ho16) += mask(i x j) @ z(j x ho16), 8 MFMA
        #pragma unroll
        for (int mt = 0; mt < 4; ++mt) {
            #pragma unroll
            for (int ks2 = 0; ks2 < 2; ++ks2) {
                union { u32 wd[4]; bf16x8 v; } m;
                u32 s0 = cs[mt][ks2].x, s1 = cs[mt][ks2].y;
                #pragma unroll
                for (int k = 0; k < 4; ++k) {
                    u32 s = (k < 2) ? s0 : s1;
                    u32 b0 = (s >> ((k & 1) * 16)) & 0xFFu;
                    u32 b1 = (s >> ((k & 1) * 16 + 8)) & 0xFFu;
                    m.wd[k] = (b0 == (u32)c ? 0x3F80u : 0u) | (b1 == (u32)c ? 0x3F800000u : 0u);
                }
                acc[mt] = __builtin_amdgcn_mfma_f32_16x16x32_bf16(m.v, b2[ks2], acc[mt], 0, 0, 0);
            }
        }
    }

    // epilogue: partial[cq][b][i][hoq*16..]
    float* pb = partial + (((size_t)cq * 64 + b) * 64) * 128 + hoq * 16;
    #pragma unroll
    for (int mt = 0; mt < 4; ++mt)
        #pragma unroll
        for (int r4 = 0; r4 < 4; ++r4)
            pb[(size_t)(mt * 16 + kg * 4 + r4) * 128 + l15] = acc[mt][r4];
}

// ---- reduce: out = bias + sum_cq partial  (512 blocks x 256 thr) ----
__global__ __launch_bounds__(256)
void gp_reduce(const float* __restrict__ partial, const float* __restrict__ bias,
               float* __restrict__ out)
{
    int gid = blockIdx.x * 256 + threadIdx.x;  // 131072 float4s
    int ho4 = gid & 31;
    float4 a = *(const float4*)(bias + ho4 * 4);
    #pragma unroll
    for (int ch = 0; ch < NCHUNK; ++ch) {
        float4 v = *(const float4*)(partial + (size_t)ch * 524288 + (size_t)gid * 4);
        a.x += v.x; a.y += v.y; a.z += v.z; a.w += v.w;
    }
    *(float4*)(out + (size_t)gid * 4) = a;
}

extern "C" void kernel_launch(void* const* d_in, const int* in_sizes, int n_in,
                              void* d_out, int out_size, void* d_ws, size_t ws_size,
                              hipStream_t stream)
{
    const float* hid  = (const float*)d_in[0];  // [64,64,128]
    const float* pos  = (const float*)d_in[1];  // [64,64,2]
    const float* W    = (const float*)d_in[2];  // [128,8192]
    const float* bias = (const float*)d_in[3];  // [128]
    float* out = (float*)d_out;

    char* ws = (char*)d_ws;
    __hip_bfloat16* Wb      = (__hip_bfloat16*)(ws);               // 2 MB
    __hip_bfloat16* Hb      = (__hip_bfloat16*)(ws + (2u << 20));  // 1 MB
    unsigned char*  cellt_g = (unsigned char*) (ws + (3u << 20));  // 256 KB
    float*          partial = (float*)         (ws + (4u << 20));  // 16 MB

    hipLaunchKernelGGL(gp_prep,   dim3(384),  dim3(256), 0, stream,
                       W, pos, hid, Wb, cellt_g, Hb);
    hipLaunchKernelGGL(gp_main,   dim3(1024), dim3(256), 0, stream,
                       Hb, cellt_g, Wb, partial);
    hipLaunchKernelGGL(gp_reduce, dim3(512),  dim3(256), 0, stream,
                       partial, bias, out);
}

// Round 11
// 39.200 us; speedup vs baseline: 4.0707x; 4.0707x over previous
//
#include <hip/hip_runtime.h>
#include <hip/hip_bf16.h>
#include <stdint.h>

// pooled[b,i,:] = bias + sum_{j!=i} W_cell(b,i,j) . hid[b,j,:]
// R11 = R10 parallelism with both R10 regressions fixed:
//  - partial layout [cq][hoq][b][i][16]: every wave writes full cache lines it
//    owns (R10's 64B half-line cross-XCD false sharing -> WRITE 212MB).
//  - __launch_bounds__(256,3) (170 VGPR) + manual static wfA/wfB double buffer
//    so the hoisted A-frags STAY in registers (R10's 128-cap remat -> FETCH 392MB).
// Wave = (b, 16-ho slice hoq, 8-cell chunk cq); 1024 blocks x 4 indep waves,
// no barriers after init. XCD swizzle bid&7 (R9-verified, FETCH 17MB).
// Inner loop per cell: 4 prefetched W-frag L2 loads, 16 MFMA, wave-private
// LDS transpose (R10-verified conflict-free zswz), 8 mask-MFMA.

typedef __attribute__((ext_vector_type(8))) short bf16x8;
typedef __attribute__((ext_vector_type(4))) float f32x4;
typedef unsigned int u32;

#define NCHUNK 8

__device__ inline unsigned short bf16bits(float x) {
    __hip_bfloat16 h = __float2bfloat16(x);
    return *reinterpret_cast<unsigned short*>(&h);
}

// zscr swizzle: bijective, conflict-free (R10: SQ_LDS_BANK_CONFLICT == 0)
__device__ inline int zswz(int jp, int l15) {
    int X = ((((jp >> 1) ^ (jp >> 2)) & 1) << 4)
          | (((jp >> 2) & 1) << 3)
          | (((jp >> 3) & 1) << 2);
    return (jp * 16 + l15) ^ X;
}

// ---- prep: 384 blocks x 256 thr (unchanged, R9/R10-verified) ----
__global__ __launch_bounds__(256)
void gp_prep(const float* __restrict__ W, const float* __restrict__ pos,
             const float* __restrict__ hid,
             __hip_bfloat16* __restrict__ Wb,      // [64][16][128][8]
             unsigned char* __restrict__ cellt_g,  // [64][64][64]
             __hip_bfloat16* __restrict__ Hb)      // [64][16][64][8]
{
    const int bid = blockIdx.x, t = threadIdx.x;
    if (bid < 256) {
        __shared__ __attribute__((aligned(16))) __hip_bfloat16 Wl[32][136];
        const int c = bid >> 2, q = bid & 3;
        #pragma unroll
        for (int it = 0; it < 4; ++it) {
            int idx = it * 256 + t;
            int r = idx >> 5, k4 = idx & 31;
            float4 v = *(const float4*)(W + (size_t)(q * 32 + r) * 8192 + c * 128 + k4 * 4);
            __hip_bfloat16* d = &Wl[r][k4 * 4];
            d[0] = __float2bfloat16(v.x); d[1] = __float2bfloat16(v.y);
            d[2] = __float2bfloat16(v.z); d[3] = __float2bfloat16(v.w);
        }
        __syncthreads();
        #pragma unroll
        for (int it = 0; it < 2; ++it) {
            int idx = it * 256 + t;           // hg(16) x hol(32)
            int hg = idx >> 5, hol = idx & 31;
            bf16x8 v = *(const bf16x8*)&Wl[hol][hg * 8];
            *(bf16x8*)(Wb + (size_t)c * 16384 + hg * 1024 + (q * 32 + hol) * 8) = v;
        }
    } else if (bid < 320) {
        __shared__ float ps[128];
        const int b = bid - 256;
        if (t < 128) ps[t] = pos[(size_t)b * 128 + t];
        __syncthreads();
        #pragma unroll
        for (int qq = 0; qq < 16; ++qq) {
            int idx = qq * 256 + t;
            int i = idx >> 6, j = idx & 63;
            float rx = ps[j * 2 + 0] - ps[i * 2 + 0];
            float ry = ps[j * 2 + 1] - ps[i * 2 + 1];
            int gx = (int)((rx + 2.0f) * 2.0f);
            int gy = (int)((ry + 2.0f) * 2.0f);
            gx = gx < 0 ? 0 : (gx > 7 ? 7 : gx);
            gy = gy < 0 ? 0 : (gy > 7 ? 7 : gy);
            cellt_g[(size_t)b * 4096 + idx] =
                (i == j) ? 255 : (unsigned char)(gx * 8 + gy);
        }
    } else {
        const int b = bid - 320;
        #pragma unroll
        for (int q = 0; q < 4; ++q) {
            int idx = q * 256 + t;            // hg(16) x j(64)
            int hg = idx >> 6, j = idx & 63;
            const float* src = hid + ((size_t)b * 64 + j) * 128 + hg * 8;
            float4 v0 = *(const float4*)src;
            float4 v1 = *(const float4*)(src + 4);
            union { unsigned short us[8]; bf16x8 v; } pk;
            pk.us[0] = bf16bits(v0.x); pk.us[1] = bf16bits(v0.y);
            pk.us[2] = bf16bits(v0.z); pk.us[3] = bf16bits(v0.w);
            pk.us[4] = bf16bits(v1.x); pk.us[5] = bf16bits(v1.y);
            pk.us[6] = bf16bits(v1.z); pk.us[7] = bf16bits(v1.w);
            *(bf16x8*)(Hb + (size_t)b * 8192 + (size_t)idx * 8) = pk.v;
        }
    }
}

// ---- main: 1024 blocks x 256 thr (4 independent waves), 170-VGPR budget ----
__global__ __launch_bounds__(256, 3)
void gp_main(const __hip_bfloat16* __restrict__ Hb,
             const unsigned char* __restrict__ cellt_g,
             const __hip_bfloat16* __restrict__ Wb,
             float* __restrict__ partial)
{
    __shared__ __attribute__((aligned(16))) u32 zscr[4][512];  // 2KB/wave

    const int bid = blockIdx.x;
    const int xcd = bid & 7;
    const int r = bid >> 3;              // blocal(8) x hoq(8) x cqg(2)
    const int blocal = r >> 4;
    const int hoq = (r >> 1) & 7;
    const int cqg = r & 1;
    const int b = xcd * 8 + blocal;

    const int t = threadIdx.x;
    const int w = t >> 6;
    const int cq = cqg * 4 + w;
    const int lane = t & 63;
    const int l15 = lane & 15, kg = lane >> 4;
    u32* zw = &zscr[w][0];

    // hoisted cellt bytes
    uint2 cs[4][2];
    #pragma unroll
    for (int mt = 0; mt < 4; ++mt)
        #pragma unroll
        for (int ks2 = 0; ks2 < 2; ++ks2)
            cs[mt][ks2] = *(const uint2*)(cellt_g + (size_t)b * 4096 +
                                          (mt * 16 + l15) * 64 + ks2 * 32 + kg * 8);

    // hoisted hid A-frags (must stay resident: 64 VGPR)
    bf16x8 a[4][4];
    #pragma unroll
    for (int jt = 0; jt < 4; ++jt)
        #pragma unroll
        for (int ks = 0; ks < 4; ++ks)
            a[jt][ks] = *(const bf16x8*)(Hb + (size_t)b * 8192 +
                                         ((ks * 4 + kg) * 64 + jt * 16 + l15) * 8);

    f32x4 acc[4];
    #pragma unroll
    for (int mt = 0; mt < 4; ++mt) acc[mt] = (f32x4){0.f, 0.f, 0.f, 0.f};

    const __hip_bfloat16* wbase = Wb + ((size_t)(kg) * 128 + hoq * 16 + l15) * 8;

    auto loadwf = [&](bf16x8 (&wf)[4], int c) {
        const __hip_bfloat16* wc = wbase + (size_t)c * 16384;
        #pragma unroll
        for (int ks = 0; ks < 4; ++ks)
            wf[ks] = *(const bf16x8*)(wc + (size_t)ks * 4 * 128 * 8);
    };

    auto compute_cell = [&](int c, bf16x8 (&wf)[4]) {
        // stage-1: z[jt] = hid(j x h) @ W_c^T(h x ho16), 16 MFMA
        f32x4 z[4];
        #pragma unroll
        for (int jt = 0; jt < 4; ++jt) z[jt] = (f32x4){0.f, 0.f, 0.f, 0.f};
        #pragma unroll
        for (int ks = 0; ks < 4; ++ks)
            #pragma unroll
            for (int jt = 0; jt < 4; ++jt)
                z[jt] = __builtin_amdgcn_mfma_f32_16x16x32_bf16(a[jt][ks], wf[ks], z[jt], 0, 0, 0);

        // pack z -> zw (R10-verified layout + swizzle)
        #pragma unroll
        for (int jt = 0; jt < 4; ++jt) {
            u32 p0 = (u32)bf16bits(z[jt][0]) | ((u32)bf16bits(z[jt][1]) << 16);
            u32 p1 = (u32)bf16bits(z[jt][2]) | ((u32)bf16bits(z[jt][3]) << 16);
            int a0 = zswz(jt * 8 + kg * 2, l15);
            zw[a0] = p0;
            zw[a0 ^ 16] = p1;
        }

        // transpose read
        bf16x8 b2[2];
        #pragma unroll
        for (int ks2 = 0; ks2 < 2; ++ks2) {
            union { u32 wd[4]; bf16x8 v; } rr;
            #pragma unroll
            for (int u = 0; u < 4; ++u)
                rr.wd[u] = zw[zswz(ks2 * 16 + kg * 4 + u, l15)];
            b2[ks2] = rr.v;
        }

        // stage-2: 8 mask-MFMA
        #pragma unroll
        for (int mt = 0; mt < 4; ++mt) {
            #pragma unroll
            for (int ks2 = 0; ks2 < 2; ++ks2) {
                union { u32 wd[4]; bf16x8 v; } m;
                u32 s0 = cs[mt][ks2].x, s1 = cs[mt][ks2].y;
                #pragma unroll
                for (int k = 0; k < 4; ++k) {
                    u32 s = (k < 2) ? s0 : s1;
                    u32 b0 = (s >> ((k & 1) * 16)) & 0xFFu;
                    u32 b1 = (s >> ((k & 1) * 16 + 8)) & 0xFFu;
                    m.wd[k] = (b0 == (u32)c ? 0x3F80u : 0u) | (b1 == (u32)c ? 0x3F800000u : 0u);
                }
                acc[mt] = __builtin_amdgcn_mfma_f32_16x16x32_bf16(m.v, b2[ks2], acc[mt], 0, 0, 0);
            }
        }
    };

    // manual static double-buffer (rule #20: no runtime-indexed reg arrays)
    bf16x8 wfA[4], wfB[4];
    const int c0 = cq * 8;
    loadwf(wfA, c0);
    #pragma unroll
    for (int cc = 0; cc < 8; cc += 2) {
        if (cc + 1 < 8) loadwf(wfB, c0 + cc + 1);
        compute_cell(c0 + cc, wfA);
        if (cc + 2 < 8) loadwf(wfA, c0 + cc + 2);
        compute_cell(c0 + cc + 1, wfB);
    }

    // epilogue: partial[cq][hoq][b][i][16] — wave-owned 4KB region, full lines
    float* pb = partial + ((((size_t)cq * 8 + hoq) * 64 + b) * 64) * 16;
    #pragma unroll
    for (int mt = 0; mt < 4; ++mt)
        #pragma unroll
        for (int r4 = 0; r4 < 4; ++r4)
            pb[(size_t)(mt * 16 + kg * 4 + r4) * 16 + l15] = acc[mt][r4];
}

// ---- reduce: out = bias + sum_cq partial  (512 blocks x 256 thr) ----
__global__ __launch_bounds__(256)
void gp_reduce(const float* __restrict__ partial, const float* __restrict__ bias,
               float* __restrict__ out)
{
    int gid = blockIdx.x * 256 + threadIdx.x;    // 131072 float4s per cq slice
    int hoq = gid >> 14;
    int b   = (gid >> 8) & 63;
    int i   = (gid >> 2) & 63;
    int e4  = gid & 3;
    float4 s = *(const float4*)(bias + hoq * 16 + e4 * 4);
    #pragma unroll
    for (int cq = 0; cq < NCHUNK; ++cq) {
        float4 v = *(const float4*)(partial + (size_t)cq * 524288 + (size_t)gid * 4);
        s.x += v.x; s.y += v.y; s.z += v.z; s.w += v.w;
    }
    *(float4*)(out + ((size_t)(b * 64 + i) * 128 + hoq * 16 + e4 * 4)) = s;
}

extern "C" void kernel_launch(void* const* d_in, const int* in_sizes, int n_in,
                              void* d_out, int out_size, void* d_ws, size_t ws_size,
                              hipStream_t stream)
{
    const float* hid  = (const float*)d_in[0];  // [64,64,128]
    const float* pos  = (const float*)d_in[1];  // [64,64,2]
    const float* W    = (const float*)d_in[2];  // [128,8192]
    const float* bias = (const float*)d_in[3];  // [128]
    float* out = (float*)d_out;

    char* ws = (char*)d_ws;
    __hip_bfloat16* Wb      = (__hip_bfloat16*)(ws);               // 2 MB
    __hip_bfloat16* Hb      = (__hip_bfloat16*)(ws + (2u << 20));  // 1 MB
    unsigned char*  cellt_g = (unsigned char*) (ws + (3u << 20));  // 256 KB
    float*          partial = (float*)         (ws + (4u << 20));  // 16 MB

    hipLaunchKernelGGL(gp_prep,   dim3(384),  dim3(256), 0, stream,
                       W, pos, hid, Wb, cellt_g, Hb);
    hipLaunchKernelGGL(gp_main,   dim3(1024), dim3(256), 0, stream,
                       Hb, cellt_g, Wb, partial);
    hipLaunchKernelGGL(gp_reduce, dim3(512),  dim3(256), 0, stream,
                       partial, bias, out);
}